// Round 1
// baseline (57.504 us; speedup 1.0000x reference)
//
#include <hip/hip_runtime.h>

// GCBFSafetyLayer: the reference's QP-projection loop uses A = L_g_h which is
// jnp.zeros(...). Every projection step is gated on (nrm > 1e-6) where
// nrm = sum(a_j^2) = 0, so u is never updated and safe_action == raw_action
// bitwise. The entire op reduces to copying raw_action (8*512*2 = 8192 fp32).

__global__ __launch_bounds__(256) void copy_f4(const float4* __restrict__ src,
                                               float4* __restrict__ dst,
                                               int n4) {
    int i = blockIdx.x * blockDim.x + threadIdx.x;
    if (i < n4) dst[i] = src[i];
}

extern "C" void kernel_launch(void* const* d_in, const int* in_sizes, int n_in,
                              void* d_out, int out_size, void* d_ws, size_t ws_size,
                              hipStream_t stream) {
    // inputs: 0=positions (8192), 1=velocities (8192), 2=obstacles (6144),
    //         3=raw_action (8192). output: safe_action (8192 fp32).
    const float4* raw = (const float4*)d_in[3];
    float4* out = (float4*)d_out;
    int n4 = out_size / 4;  // 8192 / 4 = 2048
    int block = 256;
    int grid = (n4 + block - 1) / block;
    copy_f4<<<grid, block, 0, stream>>>(raw, out, n4);
}